// Round 5
// baseline (220.944 us; speedup 1.0000x reference)
//
#include <hip/hip_runtime.h>
#include <hip/hip_bf16.h>
#include <math.h>

#define B_ROWS 4096
#define D_DIM 512
#define TWO_B 8192
#define HW_N 256
#define BASE_T 0.07f
#define ALPHA_C 0.5f
#define LOG2E 1.44269504088896340736f

typedef __bf16 v8bf __attribute__((ext_vector_type(8)));
typedef float v4f __attribute__((ext_vector_type(4)));

__device__ __forceinline__ float fast_exp2(float x) {
#if __has_builtin(__builtin_amdgcn_exp2f)
    return __builtin_amdgcn_exp2f(x);
#else
    return exp2f(x);
#endif
}

// ---------------------------------------------------------------------------
// Kernel 1: normalize, temps, pos_sim. One block (256 thr) per sample row b.
// ---------------------------------------------------------------------------
__global__ __launch_bounds__(256) void prep_kernel(
    const float* __restrict__ emb1, const float* __restrict__ emb2,
    const float* __restrict__ att, __hip_bfloat16* __restrict__ X,
    float* __restrict__ inv_temp, float* __restrict__ pos)
{
    const int b = blockIdx.x;
    const int t = threadIdx.x;
    const float* e1 = emb1 + (size_t)b * D_DIM;
    const float* e2 = emb2 + (size_t)b * D_DIM;
    float a1 = e1[t], c1 = e1[t + 256];
    float a2 = e2[t], c2 = e2[t + 256];
    float av = att[(size_t)b * HW_N + t];
    float s1 = a1 * a1 + c1 * c1;
    float s2 = a2 * a2 + c2 * c2;
    float s12 = a1 * a2 + c1 * c2;
    #pragma unroll
    for (int m = 1; m < 64; m <<= 1) {
        s1  += __shfl_xor(s1, m, 64);
        s2  += __shfl_xor(s2, m, 64);
        s12 += __shfl_xor(s12, m, 64);
        av  += __shfl_xor(av, m, 64);
    }
    __shared__ float red[4][4];
    const int w = t >> 6, lane = t & 63;
    if (lane == 0) { red[w][0] = s1; red[w][1] = s2; red[w][2] = s12; red[w][3] = av; }
    __syncthreads();
    const float T1  = red[0][0] + red[1][0] + red[2][0] + red[3][0];
    const float T2  = red[0][1] + red[1][1] + red[2][1] + red[3][1];
    const float T12 = red[0][2] + red[1][2] + red[2][2] + red[3][2];
    const float Ta  = red[0][3] + red[1][3] + red[2][3] + red[3][3];
    const float i1 = 1.0f / fmaxf(sqrtf(T1), 1e-12f);
    const float i2 = 1.0f / fmaxf(sqrtf(T2), 1e-12f);
    const float it = 1.0f / (BASE_T * (1.0f + ALPHA_C * (Ta * (1.0f / 256.0f))));
    __hip_bfloat16* x1 = X + (size_t)b * D_DIM;
    __hip_bfloat16* x2 = X + (size_t)(b + B_ROWS) * D_DIM;
    x1[t]       = __float2bfloat16(a1 * i1);
    x1[t + 256] = __float2bfloat16(c1 * i1);
    x2[t]       = __float2bfloat16(a2 * i2);
    x2[t + 256] = __float2bfloat16(c2 * i2);
    if (t == 0) {
        inv_temp[b] = it * LOG2E;
        inv_temp[b + B_ROWS] = it * LOG2E;
        pos[b] = (T12 * i1 * i2) * it;       // ln units
    }
}

// ---------------------------------------------------------------------------
// Kernel 2: triangular Gram (rb<=cb), NO LDS / NO BARRIERS.
// Each wave loads its MFMA fragments directly from global (perfectly
// coalesced: 64 lanes x 16B = 16 fully-used cachelines per load), with a
// BK=64 double-buffered register pipeline. Waves fully independent.
// Fused exp row/col sums as before.
// ---------------------------------------------------------------------------
__global__ __launch_bounds__(256, 2) void gram_kernel(
    const __hip_bfloat16* __restrict__ X,
    const float* __restrict__ inv_temp,
    float* __restrict__ partial)
{
    // --- triangular index: bid -> (rb, cb), rb <= cb ---
    const int bid = blockIdx.x;
    int rb = (int)((129.0f - sqrtf(129.0f * 129.0f - 8.0f * (float)bid)) * 0.5f);
    rb = rb < 0 ? 0 : (rb > 63 ? 63 : rb);
    while (rb > 0 && (rb * (129 - rb)) / 2 > bid) rb--;
    while (rb < 63 && ((rb + 1) * (129 - (rb + 1))) / 2 <= bid) rb++;
    const int cb = rb + (bid - (rb * (129 - rb)) / 2);

    const int rowBase = rb * 128;
    const int colBase = cb * 128;

    const int tid  = threadIdx.x;
    const int w    = tid >> 6;
    const int lane = tid & 63;
    const int quad = lane >> 4;
    const int t    = lane & 15;
    const int wm   = w >> 1;
    const int wn   = w & 1;

    // per-lane fragment base pointers (A: rows, B: cols; X is row-major,
    // sim = X X^T so both operands use the identical row layout)
    const __hip_bfloat16* ap[4];
    const __hip_bfloat16* bp[4];
    #pragma unroll
    for (int mi = 0; mi < 4; mi++)
        ap[mi] = X + (size_t)(rowBase + wm * 64 + mi * 16 + t) * D_DIM + quad * 8;
    #pragma unroll
    for (int ni = 0; ni < 4; ni++)
        bp[ni] = X + (size_t)(colBase + wn * 64 + ni * 16 + t) * D_DIM + quad * 8;

    v4f acc[4][4];
    #pragma unroll
    for (int a = 0; a < 4; a++)
        #pragma unroll
        for (int b2 = 0; b2 < 4; b2++)
            acc[a][b2] = v4f{0.0f, 0.0f, 0.0f, 0.0f};

    // double-buffered fragment registers: [buf][mi][ks], ks = 32-elem step
    v8bf abuf[2][4][2], bbuf[2][4][2];
    #pragma unroll
    for (int mi = 0; mi < 4; mi++) {
        abuf[0][mi][0] = *(const v8bf*)(ap[mi]);
        abuf[0][mi][1] = *(const v8bf*)(ap[mi] + 32);
        bbuf[0][mi][0] = *(const v8bf*)(bp[mi]);
        bbuf[0][mi][1] = *(const v8bf*)(bp[mi] + 32);
    }

    #pragma unroll
    for (int p = 0; p < 8; p++) {           // 8 phases of BK=64
        const int cur = p & 1, nxt = cur ^ 1;
        if (p < 7) {
            const int ko = (p + 1) * 64;
            #pragma unroll
            for (int mi = 0; mi < 4; mi++) {
                abuf[nxt][mi][0] = *(const v8bf*)(ap[mi] + ko);
                abuf[nxt][mi][1] = *(const v8bf*)(ap[mi] + ko + 32);
                bbuf[nxt][mi][0] = *(const v8bf*)(bp[mi] + ko);
                bbuf[nxt][mi][1] = *(const v8bf*)(bp[mi] + ko + 32);
            }
        }
        #pragma unroll
        for (int ks = 0; ks < 2; ks++)
            #pragma unroll
            for (int mi = 0; mi < 4; mi++)
                #pragma unroll
                for (int ni = 0; ni < 4; ni++)
                    acc[mi][ni] = __builtin_amdgcn_mfma_f32_16x16x32_bf16(
                        abuf[cur][mi][ks], bbuf[cur][ni][ks], acc[mi][ni], 0, 0, 0);
    }

    // ---- Epilogue 1: row sums (temp_i), slice 2*cb+wn ----
    v4f itv[4];
    #pragma unroll
    for (int mi = 0; mi < 4; mi++)
        itv[mi] = *(const v4f*)&inv_temp[rowBase + wm * 64 + mi * 16 + quad * 4];

    float* prow = partial + (size_t)(cb * 2 + wn) * TWO_B;
    #pragma unroll
    for (int mi = 0; mi < 4; mi++) {
        #pragma unroll
        for (int r = 0; r < 4; r++) {
            const int i = rowBase + wm * 64 + mi * 16 + quad * 4 + r;
            const float it = itv[mi][r];
            float s = 0.0f;
            #pragma unroll
            for (int ni = 0; ni < 4; ni++) {
                const int j = colBase + wn * 64 + ni * 16 + t;
                const float v = fast_exp2(acc[mi][ni][r] * it);
                s += (i == j) ? 0.0f : v;
            }
            s += __shfl_xor(s, 1, 64);
            s += __shfl_xor(s, 2, 64);
            s += __shfl_xor(s, 4, 64);
            s += __shfl_xor(s, 8, 64);
            if (t == 0) prow[i] = s;
        }
    }

    // ---- Epilogue 2 (off-diag): col sums (temp_j), slice 2*rb+wm ----
    if (rb != cb) {
        float itj[4];
        float cs[4] = {0.0f, 0.0f, 0.0f, 0.0f};
        #pragma unroll
        for (int ni = 0; ni < 4; ni++)
            itj[ni] = inv_temp[colBase + wn * 64 + ni * 16 + t];
        #pragma unroll
        for (int mi = 0; mi < 4; mi++)
            #pragma unroll
            for (int r = 0; r < 4; r++)
                #pragma unroll
                for (int ni = 0; ni < 4; ni++)
                    cs[ni] += fast_exp2(acc[mi][ni][r] * itj[ni]);
        float* pcol = partial + (size_t)(rb * 2 + wm) * TWO_B;
        #pragma unroll
        for (int ni = 0; ni < 4; ni++) {
            cs[ni] += __shfl_xor(cs[ni], 16, 64);
            cs[ni] += __shfl_xor(cs[ni], 32, 64);
            if (quad == 0) pcol[colBase + wn * 64 + ni * 16 + t] = cs[ni];
        }
    }
}

// ---------------------------------------------------------------------------
// Kernel 3a: denom = sum of 128 slices; loss_i = log(denom) - pos; block sums
// ---------------------------------------------------------------------------
__global__ __launch_bounds__(256) void finish1(
    const float* __restrict__ partial, const float* __restrict__ pos,
    float* __restrict__ blockSums)
{
    const int i = blockIdx.x * 256 + threadIdx.x;
    float d = 0.0f;
    #pragma unroll 8
    for (int s = 0; s < 128; s++) d += partial[(size_t)s * TWO_B + i];
    float li = logf(d) - pos[i & (B_ROWS - 1)];
    #pragma unroll
    for (int m = 1; m < 64; m <<= 1) li += __shfl_xor(li, m, 64);
    __shared__ float red[4];
    const int w = threadIdx.x >> 6, lane = threadIdx.x & 63;
    if (lane == 0) red[w] = li;
    __syncthreads();
    if (threadIdx.x == 0) blockSums[blockIdx.x] = red[0] + red[1] + red[2] + red[3];
}

__global__ void finish2(const float* __restrict__ blockSums, float* __restrict__ out)
{
    const int lane = threadIdx.x;
    float v = (lane < 32) ? blockSums[lane] : 0.0f;
    #pragma unroll
    for (int m = 1; m < 64; m <<= 1) v += __shfl_xor(v, m, 64);
    if (lane == 0) out[0] = v * (1.0f / 8192.0f);
}

// ---------------------------------------------------------------------------
extern "C" void kernel_launch(void* const* d_in, const int* in_sizes, int n_in,
                              void* d_out, int out_size, void* d_ws, size_t ws_size,
                              hipStream_t stream) {
    const float* emb1 = (const float*)d_in[0];
    const float* emb2 = (const float*)d_in[1];
    const float* att  = (const float*)d_in[2];
    float* out = (float*)d_out;

    char* ws = (char*)d_ws;
    __hip_bfloat16* X  = (__hip_bfloat16*)ws;
    float* inv_temp    = (float*)(ws + 8388608);
    float* pos         = (float*)(ws + 8388608 + 32768);
    float* partial     = (float*)(ws + 8388608 + 32768 + 16384);
    float* blockSums   = (float*)(ws + 8388608 + 32768 + 16384 + 4194304);

    prep_kernel<<<B_ROWS, 256, 0, stream>>>(emb1, emb2, att, X, inv_temp, pos);
    gram_kernel<<<2080, 256, 0, stream>>>(X, inv_temp, partial);
    finish1<<<TWO_B / 256, 256, 0, stream>>>(partial, pos, blockSums);
    finish2<<<1, 64, 0, stream>>>(blockSums, out);
}

// Round 6
// 151.599 us; speedup vs baseline: 1.4574x; 1.4574x over previous
//
#include <hip/hip_runtime.h>
#include <hip/hip_bf16.h>
#include <math.h>

#define B_ROWS 4096
#define D_DIM 512
#define TWO_B 8192
#define HW_N 256
#define BASE_T 0.07f
#define ALPHA_C 0.5f
#define LOG2E 1.44269504088896340736f

typedef __bf16 v8bf __attribute__((ext_vector_type(8)));
typedef float v4f __attribute__((ext_vector_type(4)));

__device__ __forceinline__ float fast_exp2(float x) {
#if __has_builtin(__builtin_amdgcn_exp2f)
    return __builtin_amdgcn_exp2f(x);
#else
    return exp2f(x);
#endif
}

// ---------------------------------------------------------------------------
// Kernel 1: normalize, temps, pos_sim. One block (256 thr) per sample row b.
// ---------------------------------------------------------------------------
__global__ __launch_bounds__(256) void prep_kernel(
    const float* __restrict__ emb1, const float* __restrict__ emb2,
    const float* __restrict__ att, __hip_bfloat16* __restrict__ X,
    float* __restrict__ inv_temp, float* __restrict__ pos)
{
    const int b = blockIdx.x;
    const int t = threadIdx.x;
    const float* e1 = emb1 + (size_t)b * D_DIM;
    const float* e2 = emb2 + (size_t)b * D_DIM;
    float a1 = e1[t], c1 = e1[t + 256];
    float a2 = e2[t], c2 = e2[t + 256];
    float av = att[(size_t)b * HW_N + t];
    float s1 = a1 * a1 + c1 * c1;
    float s2 = a2 * a2 + c2 * c2;
    float s12 = a1 * a2 + c1 * c2;
    #pragma unroll
    for (int m = 1; m < 64; m <<= 1) {
        s1  += __shfl_xor(s1, m, 64);
        s2  += __shfl_xor(s2, m, 64);
        s12 += __shfl_xor(s12, m, 64);
        av  += __shfl_xor(av, m, 64);
    }
    __shared__ float red[4][4];
    const int w = t >> 6, lane = t & 63;
    if (lane == 0) { red[w][0] = s1; red[w][1] = s2; red[w][2] = s12; red[w][3] = av; }
    __syncthreads();
    const float T1  = red[0][0] + red[1][0] + red[2][0] + red[3][0];
    const float T2  = red[0][1] + red[1][1] + red[2][1] + red[3][1];
    const float T12 = red[0][2] + red[1][2] + red[2][2] + red[3][2];
    const float Ta  = red[0][3] + red[1][3] + red[2][3] + red[3][3];
    const float i1 = 1.0f / fmaxf(sqrtf(T1), 1e-12f);
    const float i2 = 1.0f / fmaxf(sqrtf(T2), 1e-12f);
    const float it = 1.0f / (BASE_T * (1.0f + ALPHA_C * (Ta * (1.0f / 256.0f))));
    __hip_bfloat16* x1 = X + (size_t)b * D_DIM;
    __hip_bfloat16* x2 = X + (size_t)(b + B_ROWS) * D_DIM;
    x1[t]       = __float2bfloat16(a1 * i1);
    x1[t + 256] = __float2bfloat16(c1 * i1);
    x2[t]       = __float2bfloat16(a2 * i2);
    x2[t + 256] = __float2bfloat16(c2 * i2);
    if (t == 0) {
        inv_temp[b] = it * LOG2E;
        inv_temp[b + B_ROWS] = it * LOG2E;
        pos[b] = (T12 * i1 * i2) * it;       // ln units
    }
}

// ---------------------------------------------------------------------------
// Kernel 2: triangular Gram (rb<=cb). BK=64, DOUBLE-BUFFERED glds staging,
// one barrier per phase; prefetch issued before compute so the vmcnt drain
// at the next barrier lands after a full compute phase (latency hidden).
// XOR swizzle (8-chunk rows): store chunk sc^sg, read p=(s*4+quad)^(t&7)
// -> conflict-free b128. XCD-contiguous triangular remap for L2 locality.
// ---------------------------------------------------------------------------
__device__ __forceinline__ void gload_lds16(const void* g, void* s) {
    __builtin_amdgcn_global_load_lds(
        (const __attribute__((address_space(1))) unsigned int*)g,
        (__attribute__((address_space(3))) unsigned int*)s,
        16, 0, 0);
}

__global__ __launch_bounds__(256) void gram_kernel(
    const __hip_bfloat16* __restrict__ X,
    const float* __restrict__ inv_temp,
    float* __restrict__ partial)
{
    // --- XCD-contiguous remap: 2080 = 8 XCDs x 260 contiguous tri-ids ---
    const int bid = (blockIdx.x & 7) * 260 + (blockIdx.x >> 3);
    // --- triangular index: bid -> (rb, cb), rb <= cb ---
    int rb = (int)((129.0f - sqrtf(129.0f * 129.0f - 8.0f * (float)bid)) * 0.5f);
    rb = rb < 0 ? 0 : (rb > 63 ? 63 : rb);
    while (rb > 0 && (rb * (129 - rb)) / 2 > bid) rb--;
    while (rb < 63 && ((rb + 1) * (129 - (rb + 1))) / 2 <= bid) rb++;
    const int cb = rb + (bid - (rb * (129 - rb)) / 2);

    // double-buffered: 128 rows x 64 k (128 B/row) per matrix = 16 KB each
    __shared__ __hip_bfloat16 smA[2][128 * 64];   // 32 KB
    __shared__ __hip_bfloat16 smB[2][128 * 64];   // 32 KB

    const int rowBase = rb * 128;
    const int colBase = cb * 128;

    const int tid  = threadIdx.x;
    const int w    = tid >> 6;
    const int lane = tid & 63;
    const int quad = lane >> 4;
    const int t    = lane & 15;
    const int wm   = w >> 1;
    const int wn   = w & 1;

    // staging roles: each glds covers 8 rows x 8 chunks(16B) = 1 KB
    const int sg = lane >> 3;       // 0..7 row-in-group
    const int sc = lane & 7;        // 0..7 chunk
    const int gc = sc ^ sg;         // XOR swizzle via global address

    const __hip_bfloat16* Arow0 = X + (size_t)rowBase * D_DIM;
    const __hip_bfloat16* Brow0 = X + (size_t)colBase * D_DIM;

    v4f acc[4][4];
    #pragma unroll
    for (int a = 0; a < 4; a++)
        #pragma unroll
        for (int b2 = 0; b2 < 4; b2++)
            acc[a][b2] = v4f{0.0f, 0.0f, 0.0f, 0.0f};

    // stage phase 0 into buffer 0
    #pragma unroll
    for (int j = 0; j < 4; j++) {
        const int g = w * 4 + j;             // row group 0..15 (8 rows each)
        const int r = g * 8 + sg;
        gload_lds16(Arow0 + (size_t)r * D_DIM + gc * 8, &smA[0][g * 512]);
        gload_lds16(Brow0 + (size_t)r * D_DIM + gc * 8, &smB[0][g * 512]);
    }

    for (int kk = 0; kk < 8; kk++) {
        const int cur = kk & 1;
        __syncthreads();   // drains glds issued a full compute phase ago
        if (kk < 7) {
            const int ko = (kk + 1) * 64;
            #pragma unroll
            for (int j = 0; j < 4; j++) {
                const int g = w * 4 + j;
                const int r = g * 8 + sg;
                gload_lds16(Arow0 + (size_t)r * D_DIM + ko + gc * 8,
                            &smA[cur ^ 1][g * 512]);
                gload_lds16(Brow0 + (size_t)r * D_DIM + ko + gc * 8,
                            &smB[cur ^ 1][g * 512]);
            }
        }
        #pragma unroll
        for (int s = 0; s < 2; s++) {
            v8bf af[4], bf[4];
            const int p = (s * 4 + quad) ^ (t & 7);
            #pragma unroll
            for (int mi = 0; mi < 4; mi++)
                af[mi] = *(const v8bf*)&smA[cur][(wm * 64 + mi * 16 + t) * 64 + p * 8];
            #pragma unroll
            for (int ni = 0; ni < 4; ni++)
                bf[ni] = *(const v8bf*)&smB[cur][(wn * 64 + ni * 16 + t) * 64 + p * 8];
            #pragma unroll
            for (int mi = 0; mi < 4; mi++)
                #pragma unroll
                for (int ni = 0; ni < 4; ni++)
                    acc[mi][ni] = __builtin_amdgcn_mfma_f32_16x16x32_bf16(
                        af[mi], bf[ni], acc[mi][ni], 0, 0, 0);
        }
    }

    // ---- Epilogue 1: row sums (temp_i), slice 2*cb+wn ----
    v4f itv[4];
    #pragma unroll
    for (int mi = 0; mi < 4; mi++)
        itv[mi] = *(const v4f*)&inv_temp[rowBase + wm * 64 + mi * 16 + quad * 4];

    float* prow = partial + (size_t)(cb * 2 + wn) * TWO_B;
    #pragma unroll
    for (int mi = 0; mi < 4; mi++) {
        #pragma unroll
        for (int r = 0; r < 4; r++) {
            const int i = rowBase + wm * 64 + mi * 16 + quad * 4 + r;
            const float it = itv[mi][r];
            float s = 0.0f;
            #pragma unroll
            for (int ni = 0; ni < 4; ni++) {
                const int j = colBase + wn * 64 + ni * 16 + t;
                const float v = fast_exp2(acc[mi][ni][r] * it);
                s += (i == j) ? 0.0f : v;
            }
            s += __shfl_xor(s, 1, 64);
            s += __shfl_xor(s, 2, 64);
            s += __shfl_xor(s, 4, 64);
            s += __shfl_xor(s, 8, 64);
            if (t == 0) prow[i] = s;
        }
    }

    // ---- Epilogue 2 (off-diag): col sums (temp_j), slice 2*rb+wm ----
    if (rb != cb) {
        float itj[4];
        float cs[4] = {0.0f, 0.0f, 0.0f, 0.0f};
        #pragma unroll
        for (int ni = 0; ni < 4; ni++)
            itj[ni] = inv_temp[colBase + wn * 64 + ni * 16 + t];
        #pragma unroll
        for (int mi = 0; mi < 4; mi++)
            #pragma unroll
            for (int r = 0; r < 4; r++)
                #pragma unroll
                for (int ni = 0; ni < 4; ni++)
                    cs[ni] += fast_exp2(acc[mi][ni][r] * itj[ni]);
        float* pcol = partial + (size_t)(rb * 2 + wm) * TWO_B;
        #pragma unroll
        for (int ni = 0; ni < 4; ni++) {
            cs[ni] += __shfl_xor(cs[ni], 16, 64);
            cs[ni] += __shfl_xor(cs[ni], 32, 64);
            if (quad == 0) pcol[colBase + wn * 64 + ni * 16 + t] = cs[ni];
        }
    }
}

// ---------------------------------------------------------------------------
// Kernel 3a: denom = sum of 128 slices; loss_i = log(denom) - pos; block sums
// ---------------------------------------------------------------------------
__global__ __launch_bounds__(256) void finish1(
    const float* __restrict__ partial, const float* __restrict__ pos,
    float* __restrict__ blockSums)
{
    const int i = blockIdx.x * 256 + threadIdx.x;
    float d = 0.0f;
    #pragma unroll 8
    for (int s = 0; s < 128; s++) d += partial[(size_t)s * TWO_B + i];
    float li = logf(d) - pos[i & (B_ROWS - 1)];
    #pragma unroll
    for (int m = 1; m < 64; m <<= 1) li += __shfl_xor(li, m, 64);
    __shared__ float red[4];
    const int w = threadIdx.x >> 6, lane = threadIdx.x & 63;
    if (lane == 0) red[w] = li;
    __syncthreads();
    if (threadIdx.x == 0) blockSums[blockIdx.x] = red[0] + red[1] + red[2] + red[3];
}

__global__ void finish2(const float* __restrict__ blockSums, float* __restrict__ out)
{
    const int lane = threadIdx.x;
    float v = (lane < 32) ? blockSums[lane] : 0.0f;
    #pragma unroll
    for (int m = 1; m < 64; m <<= 1) v += __shfl_xor(v, m, 64);
    if (lane == 0) out[0] = v * (1.0f / 8192.0f);
}

// ---------------------------------------------------------------------------
extern "C" void kernel_launch(void* const* d_in, const int* in_sizes, int n_in,
                              void* d_out, int out_size, void* d_ws, size_t ws_size,
                              hipStream_t stream) {
    const float* emb1 = (const float*)d_in[0];
    const float* emb2 = (const float*)d_in[1];
    const float* att  = (const float*)d_in[2];
    float* out = (float*)d_out;

    char* ws = (char*)d_ws;
    __hip_bfloat16* X  = (__hip_bfloat16*)ws;
    float* inv_temp    = (float*)(ws + 8388608);
    float* pos         = (float*)(ws + 8388608 + 32768);
    float* partial     = (float*)(ws + 8388608 + 32768 + 16384);
    float* blockSums   = (float*)(ws + 8388608 + 32768 + 16384 + 4194304);

    prep_kernel<<<B_ROWS, 256, 0, stream>>>(emb1, emb2, att, X, inv_temp, pos);
    gram_kernel<<<2080, 256, 0, stream>>>(X, inv_temp, partial);
    finish1<<<TWO_B / 256, 256, 0, stream>>>(partial, pos, blockSums);
    finish2<<<1, 64, 0, stream>>>(blockSums, out);
}

// Round 7
// 144.619 us; speedup vs baseline: 1.5278x; 1.0483x over previous
//
#include <hip/hip_runtime.h>
#include <hip/hip_bf16.h>
#include <math.h>

#define B_ROWS 4096
#define D_DIM 512
#define TWO_B 8192
#define HW_N 256
#define BASE_T 0.07f
#define ALPHA_C 0.5f
#define LOG2E 1.44269504088896340736f

typedef __bf16 v8bf __attribute__((ext_vector_type(8)));
typedef float v4f __attribute__((ext_vector_type(4)));
typedef unsigned int v4u __attribute__((ext_vector_type(4)));

__device__ __forceinline__ float fast_exp2(float x) {
#if __has_builtin(__builtin_amdgcn_exp2f)
    return __builtin_amdgcn_exp2f(x);
#else
    return exp2f(x);
#endif
}

// ---------------------------------------------------------------------------
// Kernel 1: normalize, temps, pos_sim. One block (256 thr) per sample row b.
// ---------------------------------------------------------------------------
__global__ __launch_bounds__(256) void prep_kernel(
    const float* __restrict__ emb1, const float* __restrict__ emb2,
    const float* __restrict__ att, __hip_bfloat16* __restrict__ X,
    float* __restrict__ inv_temp, float* __restrict__ pos)
{
    const int b = blockIdx.x;
    const int t = threadIdx.x;
    const float* e1 = emb1 + (size_t)b * D_DIM;
    const float* e2 = emb2 + (size_t)b * D_DIM;
    float a1 = e1[t], c1 = e1[t + 256];
    float a2 = e2[t], c2 = e2[t + 256];
    float av = att[(size_t)b * HW_N + t];
    float s1 = a1 * a1 + c1 * c1;
    float s2 = a2 * a2 + c2 * c2;
    float s12 = a1 * a2 + c1 * c2;
    #pragma unroll
    for (int m = 1; m < 64; m <<= 1) {
        s1  += __shfl_xor(s1, m, 64);
        s2  += __shfl_xor(s2, m, 64);
        s12 += __shfl_xor(s12, m, 64);
        av  += __shfl_xor(av, m, 64);
    }
    __shared__ float red[4][4];
    const int w = t >> 6, lane = t & 63;
    if (lane == 0) { red[w][0] = s1; red[w][1] = s2; red[w][2] = s12; red[w][3] = av; }
    __syncthreads();
    const float T1  = red[0][0] + red[1][0] + red[2][0] + red[3][0];
    const float T2  = red[0][1] + red[1][1] + red[2][1] + red[3][1];
    const float T12 = red[0][2] + red[1][2] + red[2][2] + red[3][2];
    const float Ta  = red[0][3] + red[1][3] + red[2][3] + red[3][3];
    const float i1 = 1.0f / fmaxf(sqrtf(T1), 1e-12f);
    const float i2 = 1.0f / fmaxf(sqrtf(T2), 1e-12f);
    const float it = 1.0f / (BASE_T * (1.0f + ALPHA_C * (Ta * (1.0f / 256.0f))));
    __hip_bfloat16* x1 = X + (size_t)b * D_DIM;
    __hip_bfloat16* x2 = X + (size_t)(b + B_ROWS) * D_DIM;
    x1[t]       = __float2bfloat16(a1 * i1);
    x1[t + 256] = __float2bfloat16(c1 * i1);
    x2[t]       = __float2bfloat16(a2 * i2);
    x2[t + 256] = __float2bfloat16(c2 * i2);
    if (t == 0) {
        inv_temp[b] = it * LOG2E;
        inv_temp[b + B_ROWS] = it * LOG2E;
        pos[b] = (T12 * i1 * i2) * it;       // ln units
    }
}

// ---------------------------------------------------------------------------
// Kernel 2: triangular Gram (rb<=cb). R4 shape: BK=128, 4 fat phases,
// single 64KB LDS (2 blocks/CU), proven XOR swizzle + coalesced staging.
// NEW: global->VGPR->LDS staging with phase p+1 loads issued BEFORE phase
// p's compute, so both per-phase barriers' forced vmcnt(0) drains land
// ~800 cyc after issue (hidden). XCD-contiguous triangular remap.
// ---------------------------------------------------------------------------
__global__ __launch_bounds__(256) void gram_kernel(
    const __hip_bfloat16* __restrict__ X,
    const float* __restrict__ inv_temp,
    float* __restrict__ partial)
{
    // --- XCD-contiguous remap: 2080 = 8 XCDs x 260 contiguous tri-ids ---
    const int bid = (blockIdx.x & 7) * 260 + (blockIdx.x >> 3);
    // --- triangular index: bid -> (rb, cb), rb <= cb ---
    int rb = (int)((129.0f - sqrtf(129.0f * 129.0f - 8.0f * (float)bid)) * 0.5f);
    rb = rb < 0 ? 0 : (rb > 63 ? 63 : rb);
    while (rb > 0 && (rb * (129 - rb)) / 2 > bid) rb--;
    while (rb < 63 && ((rb + 1) * (129 - (rb + 1))) / 2 <= bid) rb++;
    const int cb = rb + (bid - (rb * (129 - rb)) / 2);

    // 128 rows x 128 k-elems (256 B/row) each: 32 KB + 32 KB
    __shared__ __hip_bfloat16 smA[128 * 128];
    __shared__ __hip_bfloat16 smB[128 * 128];

    const int rowBase = rb * 128;
    const int colBase = cb * 128;

    const int tid  = threadIdx.x;
    const int w    = tid >> 6;
    const int lane = tid & 63;
    const int quad = lane >> 4;
    const int t    = lane & 15;
    const int wm   = w >> 1;
    const int wn   = w & 1;

    // staging roles: per reg, a wave covers 4 rows x 16 chunks(16B) = 1 KB
    const int srow   = lane >> 4;   // 0..3
    const int schunk = lane & 15;   // 0..15

    const __hip_bfloat16* Arow0 = X + (size_t)rowBase * D_DIM;
    const __hip_bfloat16* Brow0 = X + (size_t)colBase * D_DIM;

    // per-lane global source addresses (8 row-groups for A, 8 for B)
    const v4u* gA[8]; const v4u* gB[8];
    #pragma unroll
    for (int j = 0; j < 8; j++) {
        const int g = w * 8 + j;            // 0..31 row group (4 rows)
        const int r = g * 4 + srow;
        const int gc = schunk ^ (r & 15);   // XOR swizzle via global chunk
        gA[j] = (const v4u*)(Arow0 + (size_t)r * D_DIM + gc * 8);
        gB[j] = (const v4u*)(Brow0 + (size_t)r * D_DIM + gc * 8);
    }

    v4f acc[4][4];
    #pragma unroll
    for (int a = 0; a < 4; a++)
        #pragma unroll
        for (int b2 = 0; b2 < 4; b2++)
            acc[a][b2] = v4f{0.0f, 0.0f, 0.0f, 0.0f};

    // preload phase 0 into staging registers
    v4u rA[8], rB[8];
    #pragma unroll
    for (int j = 0; j < 8; j++) { rA[j] = gA[j][0]; rB[j] = gB[j][0]; }

    for (int p = 0; p < 4; p++) {
        // commit staged registers to LDS (vmcnt waits here are for loads
        // issued a full compute phase ago -> hidden, except phase 0)
        #pragma unroll
        for (int j = 0; j < 8; j++) {
            const int g = w * 8 + j;
            *(v4u*)&smA[g * 512 + lane * 8] = rA[j];
            *(v4u*)&smB[g * 512 + lane * 8] = rB[j];
        }
        __syncthreads();    // nothing outstanding in vmem queue: cheap

        if (p < 3) {        // issue next phase's loads BEFORE compute
            const int ko = (p + 1) * 16;    // 128 elems = 16 v4u
            #pragma unroll
            for (int j = 0; j < 8; j++) { rA[j] = gA[j][ko >> 4 << 4 ? 0 : 0]; }
            // (expanded below without the confusing expr)
            #pragma unroll
            for (int j = 0; j < 8; j++) {
                rA[j] = *(const v4u*)((const __hip_bfloat16*)gA[j] + (p + 1) * 128);
                rB[j] = *(const v4u*)((const __hip_bfloat16*)gB[j] + (p + 1) * 128);
            }
        }

        // compute phase p: 4 k-steps x 16 MFMA (~800 cyc, hides the loads)
        #pragma unroll
        for (int s = 0; s < 4; s++) {
            v8bf af[4], bf[4];
            const int pp = (s * 4 + quad) ^ t;
            #pragma unroll
            for (int mi = 0; mi < 4; mi++)
                af[mi] = *(const v8bf*)&smA[(wm * 64 + mi * 16 + t) * 128 + pp * 8];
            #pragma unroll
            for (int ni = 0; ni < 4; ni++)
                bf[ni] = *(const v8bf*)&smB[(wn * 64 + ni * 16 + t) * 128 + pp * 8];
            #pragma unroll
            for (int mi = 0; mi < 4; mi++)
                #pragma unroll
                for (int ni = 0; ni < 4; ni++)
                    acc[mi][ni] = __builtin_amdgcn_mfma_f32_16x16x32_bf16(
                        af[mi], bf[ni], acc[mi][ni], 0, 0, 0);
        }
        __syncthreads();    // drains rA/rB loads issued ~800 cyc ago: ~free
    }

    // ---- Epilogue 1: row sums (temp_i), slice 2*cb+wn ----
    v4f itv[4];
    #pragma unroll
    for (int mi = 0; mi < 4; mi++)
        itv[mi] = *(const v4f*)&inv_temp[rowBase + wm * 64 + mi * 16 + quad * 4];

    float* prow = partial + (size_t)(cb * 2 + wn) * TWO_B;
    #pragma unroll
    for (int mi = 0; mi < 4; mi++) {
        #pragma unroll
        for (int r = 0; r < 4; r++) {
            const int i = rowBase + wm * 64 + mi * 16 + quad * 4 + r;
            const float it = itv[mi][r];
            float s = 0.0f;
            #pragma unroll
            for (int ni = 0; ni < 4; ni++) {
                const int j = colBase + wn * 64 + ni * 16 + t;
                const float v = fast_exp2(acc[mi][ni][r] * it);
                s += (i == j) ? 0.0f : v;
            }
            s += __shfl_xor(s, 1, 64);
            s += __shfl_xor(s, 2, 64);
            s += __shfl_xor(s, 4, 64);
            s += __shfl_xor(s, 8, 64);
            if (t == 0) prow[i] = s;
        }
    }

    // ---- Epilogue 2 (off-diag): col sums (temp_j), slice 2*rb+wm ----
    if (rb != cb) {
        float itj[4];
        float cs[4] = {0.0f, 0.0f, 0.0f, 0.0f};
        #pragma unroll
        for (int ni = 0; ni < 4; ni++)
            itj[ni] = inv_temp[colBase + wn * 64 + ni * 16 + t];
        #pragma unroll
        for (int mi = 0; mi < 4; mi++)
            #pragma unroll
            for (int r = 0; r < 4; r++)
                #pragma unroll
                for (int ni = 0; ni < 4; ni++)
                    cs[ni] += fast_exp2(acc[mi][ni][r] * itj[ni]);
        float* pcol = partial + (size_t)(rb * 2 + wm) * TWO_B;
        #pragma unroll
        for (int ni = 0; ni < 4; ni++) {
            cs[ni] += __shfl_xor(cs[ni], 16, 64);
            cs[ni] += __shfl_xor(cs[ni], 32, 64);
            if (quad == 0) pcol[colBase + wn * 64 + ni * 16 + t] = cs[ni];
        }
    }
}

// ---------------------------------------------------------------------------
// Kernel 3a: denom = sum of 128 slices; loss_i = log(denom) - pos; block sums
// ---------------------------------------------------------------------------
__global__ __launch_bounds__(256) void finish1(
    const float* __restrict__ partial, const float* __restrict__ pos,
    float* __restrict__ blockSums)
{
    const int i = blockIdx.x * 256 + threadIdx.x;
    float d = 0.0f;
    #pragma unroll 8
    for (int s = 0; s < 128; s++) d += partial[(size_t)s * TWO_B + i];
    float li = logf(d) - pos[i & (B_ROWS - 1)];
    #pragma unroll
    for (int m = 1; m < 64; m <<= 1) li += __shfl_xor(li, m, 64);
    __shared__ float red[4];
    const int w = threadIdx.x >> 6, lane = threadIdx.x & 63;
    if (lane == 0) red[w] = li;
    __syncthreads();
    if (threadIdx.x == 0) blockSums[blockIdx.x] = red[0] + red[1] + red[2] + red[3];
}

__global__ void finish2(const float* __restrict__ blockSums, float* __restrict__ out)
{
    const int lane = threadIdx.x;
    float v = (lane < 32) ? blockSums[lane] : 0.0f;
    #pragma unroll
    for (int m = 1; m < 64; m <<= 1) v += __shfl_xor(v, m, 64);
    if (lane == 0) out[0] = v * (1.0f / 8192.0f);
}

// ---------------------------------------------------------------------------
extern "C" void kernel_launch(void* const* d_in, const int* in_sizes, int n_in,
                              void* d_out, int out_size, void* d_ws, size_t ws_size,
                              hipStream_t stream) {
    const float* emb1 = (const float*)d_in[0];
    const float* emb2 = (const float*)d_in[1];
    const float* att  = (const float*)d_in[2];
    float* out = (float*)d_out;

    char* ws = (char*)d_ws;
    __hip_bfloat16* X  = (__hip_bfloat16*)ws;
    float* inv_temp    = (float*)(ws + 8388608);
    float* pos         = (float*)(ws + 8388608 + 32768);
    float* partial     = (float*)(ws + 8388608 + 32768 + 16384);
    float* blockSums   = (float*)(ws + 8388608 + 32768 + 16384 + 4194304);

    prep_kernel<<<B_ROWS, 256, 0, stream>>>(emb1, emb2, att, X, inv_temp, pos);
    gram_kernel<<<2080, 256, 0, stream>>>(X, inv_temp, partial);
    finish1<<<TWO_B / 256, 256, 0, stream>>>(partial, pos, blockSums);
    finish2<<<1, 64, 0, stream>>>(blockSums, out);
}

// Round 8
// 128.996 us; speedup vs baseline: 1.7128x; 1.1211x over previous
//
#include <hip/hip_runtime.h>
#include <hip/hip_bf16.h>
#include <math.h>

#define B_ROWS 4096
#define D_DIM 512
#define TWO_B 8192
#define HW_N 256
#define BASE_T 0.07f
#define ALPHA_C 0.5f
#define LOG2E 1.44269504088896340736f

typedef float v4f __attribute__((ext_vector_type(4)));

__device__ __forceinline__ float fast_exp2(float x) {
#if __has_builtin(__builtin_amdgcn_exp2f)
    return __builtin_amdgcn_exp2f(x);
#else
    return exp2f(x);
#endif
}

// ---------------------------------------------------------------------------
// Kernel 1: normalize, temps, pos_sim; write X as packed fp8 e4m3 (OCP).
// One block (256 thr) per sample row b; thread t handles dims 2t, 2t+1.
// ---------------------------------------------------------------------------
__global__ __launch_bounds__(256) void prep_kernel(
    const float* __restrict__ emb1, const float* __restrict__ emb2,
    const float* __restrict__ att, unsigned short* __restrict__ X8,
    float* __restrict__ inv_temp, float* __restrict__ pos)
{
    const int b = blockIdx.x;
    const int t = threadIdx.x;
    const float2 a1 = ((const float2*)(emb1 + (size_t)b * D_DIM))[t];
    const float2 a2 = ((const float2*)(emb2 + (size_t)b * D_DIM))[t];
    float av = att[(size_t)b * HW_N + t];
    float s1  = a1.x * a1.x + a1.y * a1.y;
    float s2  = a2.x * a2.x + a2.y * a2.y;
    float s12 = a1.x * a2.x + a1.y * a2.y;
    #pragma unroll
    for (int m = 1; m < 64; m <<= 1) {
        s1  += __shfl_xor(s1, m, 64);
        s2  += __shfl_xor(s2, m, 64);
        s12 += __shfl_xor(s12, m, 64);
        av  += __shfl_xor(av, m, 64);
    }
    __shared__ float red[4][4];
    const int w = t >> 6, lane = t & 63;
    if (lane == 0) { red[w][0] = s1; red[w][1] = s2; red[w][2] = s12; red[w][3] = av; }
    __syncthreads();
    const float T1  = red[0][0] + red[1][0] + red[2][0] + red[3][0];
    const float T2  = red[0][1] + red[1][1] + red[2][1] + red[3][1];
    const float T12 = red[0][2] + red[1][2] + red[2][2] + red[3][2];
    const float Ta  = red[0][3] + red[1][3] + red[2][3] + red[3][3];
    const float i1 = 1.0f / fmaxf(sqrtf(T1), 1e-12f);
    const float i2 = 1.0f / fmaxf(sqrtf(T2), 1e-12f);
    const float it = 1.0f / (BASE_T * (1.0f + ALPHA_C * (Ta * (1.0f / 256.0f))));
    const int p1 = __builtin_amdgcn_cvt_pk_fp8_f32(a1.x * i1, a1.y * i1, 0, false);
    const int p2 = __builtin_amdgcn_cvt_pk_fp8_f32(a2.x * i2, a2.y * i2, 0, false);
    X8[(size_t)b * 256 + t]            = (unsigned short)(p1 & 0xffff);
    X8[(size_t)(b + B_ROWS) * 256 + t] = (unsigned short)(p2 & 0xffff);
    if (t == 0) {
        inv_temp[b] = it * LOG2E;
        inv_temp[b + B_ROWS] = it * LOG2E;
        pos[b] = (T12 * i1 * i2) * it;       // ln units, exact fp32
    }
}

// ---------------------------------------------------------------------------
// Kernel 2: triangular Gram (rb<=cb) in FP8 e4m3. R4 structure: glds direct
// staging, 16B-XOR swizzle on the global address, 64 KB LDS, 2 blocks/CU —
// but BK=256 -> only 2 phases (drains halved), staged bytes halved.
// MFMA: f32_16x16x32_fp8_fp8, b64 LDS fragment reads (bandwidth-optimal:
// exactly 4 words/bank, uniform). Fused exp row/col sums unchanged.
// ---------------------------------------------------------------------------
__device__ __forceinline__ void gload_lds16(const void* g, void* s) {
    __builtin_amdgcn_global_load_lds(
        (const __attribute__((address_space(1))) unsigned int*)g,
        (__attribute__((address_space(3))) unsigned int*)s,
        16, 0, 0);
}

__global__ __launch_bounds__(256) void gram_kernel(
    const unsigned char* __restrict__ X8,
    const float* __restrict__ inv_temp,
    float* __restrict__ partial)
{
    // --- XCD-contiguous remap: 2080 = 8 XCDs x 260 contiguous tri-ids ---
    const int bid = (blockIdx.x & 7) * 260 + (blockIdx.x >> 3);
    // --- triangular index: bid -> (rb, cb), rb <= cb ---
    int rb = (int)((129.0f - sqrtf(129.0f * 129.0f - 8.0f * (float)bid)) * 0.5f);
    rb = rb < 0 ? 0 : (rb > 63 ? 63 : rb);
    while (rb > 0 && (rb * (129 - rb)) / 2 > bid) rb--;
    while (rb < 63 && ((rb + 1) * (129 - (rb + 1))) / 2 <= bid) rb++;
    const int cb = rb + (bid - (rb * (129 - rb)) / 2);

    // 128 rows x 256 B (BK=256 fp8) each: 32 KB + 32 KB
    __shared__ unsigned char smA[128 * 256];
    __shared__ unsigned char smB[128 * 256];

    const int rowBase = rb * 128;
    const int colBase = cb * 128;

    const int tid  = threadIdx.x;
    const int w    = tid >> 6;
    const int lane = tid & 63;
    const int quad = lane >> 4;
    const int t    = lane & 15;
    const int wm   = w >> 1;
    const int wn   = w & 1;

    // staging roles: each glds covers 4 rows x 16 units(16B) = 1 KB
    const int srow   = lane >> 4;   // 0..3
    const int schunk = lane & 15;   // 0..15

    const unsigned char* Arow0 = X8 + (size_t)rowBase * D_DIM;
    const unsigned char* Brow0 = X8 + (size_t)colBase * D_DIM;

    v4f acc[4][4];
    #pragma unroll
    for (int a = 0; a < 4; a++)
        #pragma unroll
        for (int b2 = 0; b2 < 4; b2++)
            acc[a][b2] = v4f{0.0f, 0.0f, 0.0f, 0.0f};

    for (int p = 0; p < 2; p++) {
        const int kk = p * 256;     // byte offset into each 512 B row
        #pragma unroll
        for (int j = 0; j < 8; j++) {
            const int g = w * 8 + j;            // row group 0..31 (4 rows)
            const int r = g * 4 + srow;
            const int gc = schunk ^ (r & 15);   // XOR swizzle via global unit
            gload_lds16(Arow0 + (size_t)r * D_DIM + kk + gc * 16, &smA[g * 1024]);
            gload_lds16(Brow0 + (size_t)r * D_DIM + kk + gc * 16, &smB[g * 1024]);
        }
        __syncthreads();

        #pragma unroll
        for (int s = 0; s < 8; s++) {
            // lane's k-chunk: global unit ug = s*2 + (quad>>1), half = quad&1
            // stored at LDS unit pu = ug ^ (row&15) = ug ^ t
            const int pu = (s * 2 + (quad >> 1)) ^ t;
            const int off = pu * 16 + (quad & 1) * 8;
            long aF[4], bF[4];
            #pragma unroll
            for (int mi = 0; mi < 4; mi++)
                aF[mi] = *(const long*)&smA[(wm * 64 + mi * 16 + t) * 256 + off];
            #pragma unroll
            for (int ni = 0; ni < 4; ni++)
                bF[ni] = *(const long*)&smB[(wn * 64 + ni * 16 + t) * 256 + off];
            #pragma unroll
            for (int mi = 0; mi < 4; mi++)
                #pragma unroll
                for (int ni = 0; ni < 4; ni++)
                    acc[mi][ni] = __builtin_amdgcn_mfma_f32_16x16x32_fp8_fp8(
                        aF[mi], bF[ni], acc[mi][ni], 0, 0, 0);
        }
        if (p == 0) __syncthreads();   // protect LDS before phase-1 overwrite
    }

    // ---- Epilogue 1: row sums (temp_i), slice 2*cb+wn ----
    v4f itv[4];
    #pragma unroll
    for (int mi = 0; mi < 4; mi++)
        itv[mi] = *(const v4f*)&inv_temp[rowBase + wm * 64 + mi * 16 + quad * 4];

    float* prow = partial + (size_t)(cb * 2 + wn) * TWO_B;
    #pragma unroll
    for (int mi = 0; mi < 4; mi++) {
        #pragma unroll
        for (int r = 0; r < 4; r++) {
            const int i = rowBase + wm * 64 + mi * 16 + quad * 4 + r;
            const float it = itv[mi][r];
            float s = 0.0f;
            #pragma unroll
            for (int ni = 0; ni < 4; ni++) {
                const int j = colBase + wn * 64 + ni * 16 + t;
                const float v = fast_exp2(acc[mi][ni][r] * it);
                s += (i == j) ? 0.0f : v;
            }
            s += __shfl_xor(s, 1, 64);
            s += __shfl_xor(s, 2, 64);
            s += __shfl_xor(s, 4, 64);
            s += __shfl_xor(s, 8, 64);
            if (t == 0) prow[i] = s;
        }
    }

    // ---- Epilogue 2 (off-diag): col sums (temp_j), slice 2*rb+wm ----
    if (rb != cb) {
        float itj[4];
        float cs[4] = {0.0f, 0.0f, 0.0f, 0.0f};
        #pragma unroll
        for (int ni = 0; ni < 4; ni++)
            itj[ni] = inv_temp[colBase + wn * 64 + ni * 16 + t];
        #pragma unroll
        for (int mi = 0; mi < 4; mi++)
            #pragma unroll
            for (int r = 0; r < 4; r++)
                #pragma unroll
                for (int ni = 0; ni < 4; ni++)
                    cs[ni] += fast_exp2(acc[mi][ni][r] * itj[ni]);
        float* pcol = partial + (size_t)(rb * 2 + wm) * TWO_B;
        #pragma unroll
        for (int ni = 0; ni < 4; ni++) {
            cs[ni] += __shfl_xor(cs[ni], 16, 64);
            cs[ni] += __shfl_xor(cs[ni], 32, 64);
            if (quad == 0) pcol[colBase + wn * 64 + ni * 16 + t] = cs[ni];
        }
    }
}

// ---------------------------------------------------------------------------
// Kernel 3a: denom = sum of 128 slices; loss_i = log(denom) - pos; block sums
// ---------------------------------------------------------------------------
__global__ __launch_bounds__(256) void finish1(
    const float* __restrict__ partial, const float* __restrict__ pos,
    float* __restrict__ blockSums)
{
    const int i = blockIdx.x * 256 + threadIdx.x;
    float d = 0.0f;
    #pragma unroll 8
    for (int s = 0; s < 128; s++) d += partial[(size_t)s * TWO_B + i];
    float li = logf(d) - pos[i & (B_ROWS - 1)];
    #pragma unroll
    for (int m = 1; m < 64; m <<= 1) li += __shfl_xor(li, m, 64);
    __shared__ float red[4];
    const int w = threadIdx.x >> 6, lane = threadIdx.x & 63;
    if (lane == 0) red[w] = li;
    __syncthreads();
    if (threadIdx.x == 0) blockSums[blockIdx.x] = red[0] + red[1] + red[2] + red[3];
}

__global__ void finish2(const float* __restrict__ blockSums, float* __restrict__ out)
{
    const int lane = threadIdx.x;
    float v = (lane < 32) ? blockSums[lane] : 0.0f;
    #pragma unroll
    for (int m = 1; m < 64; m <<= 1) v += __shfl_xor(v, m, 64);
    if (lane == 0) out[0] = v * (1.0f / 8192.0f);
}

// ---------------------------------------------------------------------------
extern "C" void kernel_launch(void* const* d_in, const int* in_sizes, int n_in,
                              void* d_out, int out_size, void* d_ws, size_t ws_size,
                              hipStream_t stream) {
    const float* emb1 = (const float*)d_in[0];
    const float* emb2 = (const float*)d_in[1];
    const float* att  = (const float*)d_in[2];
    float* out = (float*)d_out;

    char* ws = (char*)d_ws;
    // layout: X8 fp8 [8192*512] = 4,194,304 B
    //         inv_temp f32 [8192]      -> +32,768
    //         pos f32 [4096]           -> +16,384
    //         partial f32 [128*8192]   -> +4,194,304
    //         blockSums f32 [32]       -> +128
    unsigned short* X8 = (unsigned short*)ws;
    float* inv_temp    = (float*)(ws + 4194304);
    float* pos         = (float*)(ws + 4194304 + 32768);
    float* partial     = (float*)(ws + 4194304 + 32768 + 16384);
    float* blockSums   = (float*)(ws + 4194304 + 32768 + 16384 + 4194304);

    prep_kernel<<<B_ROWS, 256, 0, stream>>>(emb1, emb2, att, X8, inv_temp, pos);
    gram_kernel<<<2080, 256, 0, stream>>>((const unsigned char*)X8, inv_temp, partial);
    finish1<<<TWO_B / 256, 256, 0, stream>>>(partial, pos, blockSums);
    finish2<<<1, 64, 0, stream>>>(blockSums, out);
}